// Round 1
// baseline (213.463 us; speedup 1.0000x reference)
//
#include <hip/hip_runtime.h>

typedef __bf16 bf16;
typedef __bf16 bf16x8 __attribute__((ext_vector_type(8)));
typedef float  f32x4  __attribute__((ext_vector_type(4)));

#define T_SEQ   2048
#define D_HEAD  64
#define NH      16
#define BATCH   2
#define BH      32            // BATCH*NH
#define C_EMB   1024
#define N_TOT   3072
#define WS_STRIDE (BH * T_SEQ * D_HEAD)   // 4,194,304 elems per q/k/v plane

__device__ __forceinline__ bf16x8 cvt8(float4 a, float4 b) {
    bf16x8 r;
    r[0] = (__bf16)a.x; r[1] = (__bf16)a.y; r[2] = (__bf16)a.z; r[3] = (__bf16)a.w;
    r[4] = (__bf16)b.x; r[5] = (__bf16)b.y; r[6] = (__bf16)b.z; r[7] = (__bf16)b.w;
    return r;
}

// ---------------------------------------------------------------------------
// Kernel 1: qkv = x @ W^T + b   (fp32 in, bf16 out to ws as [which][BH][T][D])
// 128x128 tile, BK=32, 256 thr (2x2 waves), 16x16x32 bf16 MFMA.
// ---------------------------------------------------------------------------
__global__ __launch_bounds__(256) void qkv_gemm(
    const float* __restrict__ x, const float* __restrict__ W,
    const float* __restrict__ bias, bf16* __restrict__ ws)
{
    __shared__ bf16 As[128 * 40];   // ld=40: (20*row + 4g) dwords -> uniform banks
    __shared__ bf16 Bs[128 * 40];

    const int tid  = threadIdx.x;
    const int lane = tid & 63;
    const int w    = tid >> 6;
    const int wm   = w >> 1, wn = w & 1;
    const int l15  = lane & 15, l4 = lane >> 4;
    const int bm   = blockIdx.x / 24, bn = blockIdx.x % 24;

    // staging: thread -> (row 0..127, col half 0/16)
    const int srow = tid >> 1;
    const int scol = (tid & 1) * 16;
    const float* xg = x + (size_t)(bm * 128 + srow) * 1024 + scol;
    const float* wg = W + (size_t)(bn * 128 + srow) * 1024 + scol;
    bf16* asw = &As[srow * 40 + scol];
    bf16* bsw = &Bs[srow * 40 + scol];

    f32x4 acc[4][4];
#pragma unroll
    for (int i = 0; i < 4; i++)
#pragma unroll
        for (int j = 0; j < 4; j++) acc[i][j] = (f32x4){0.f, 0.f, 0.f, 0.f};

    float bv[4];
#pragma unroll
    for (int j = 0; j < 4; j++) bv[j] = bias[bn * 128 + wn * 64 + j * 16 + l15];

    for (int kk = 0; kk < 32; ++kk) {
        const float* xp = xg + kk * 32;
        const float* wp = wg + kk * 32;
        float4 a0 = *(const float4*)(xp + 0);
        float4 a1 = *(const float4*)(xp + 4);
        float4 a2 = *(const float4*)(xp + 8);
        float4 a3 = *(const float4*)(xp + 12);
        float4 b0 = *(const float4*)(wp + 0);
        float4 b1 = *(const float4*)(wp + 4);
        float4 b2 = *(const float4*)(wp + 8);
        float4 b3 = *(const float4*)(wp + 12);

        __syncthreads();   // prev iteration's fragment reads complete
        *(bf16x8*)(asw + 0) = cvt8(a0, a1);
        *(bf16x8*)(asw + 8) = cvt8(a2, a3);
        *(bf16x8*)(bsw + 0) = cvt8(b0, b1);
        *(bf16x8*)(bsw + 8) = cvt8(b2, b3);
        __syncthreads();   // staging visible

        bf16x8 aF[4], bF[4];
#pragma unroll
        for (int s = 0; s < 4; s++) {
            aF[s] = *(const bf16x8*)&As[(wm * 64 + s * 16 + l15) * 40 + l4 * 8];
            bF[s] = *(const bf16x8*)&Bs[(wn * 64 + s * 16 + l15) * 40 + l4 * 8];
        }
#pragma unroll
        for (int i = 0; i < 4; i++)
#pragma unroll
            for (int j = 0; j < 4; j++)
                acc[i][j] = __builtin_amdgcn_mfma_f32_16x16x32_bf16(
                    aF[i], bF[j], acc[i][j], 0, 0, 0);
    }

    // epilogue: +bias, scatter bf16 into ws [which][b,h][t][d]
#pragma unroll
    for (int i = 0; i < 4; i++) {
#pragma unroll
        for (int j = 0; j < 4; j++) {
            const int n     = bn * 128 + wn * 64 + j * 16 + l15;
            const int which = n >> 10;
            const int cc    = n & 1023;
            const int h     = cc >> 6, d = cc & 63;
#pragma unroll
            for (int r = 0; r < 4; r++) {
                const int m  = bm * 128 + wm * 64 + i * 16 + l4 * 4 + r;
                const int bi = m >> 11, t = m & 2047;
                const float v = acc[i][j][r] + bv[j];
                ws[which * WS_STRIDE + ((bi * NH + h) * T_SEQ + t) * D_HEAD + d] = (__bf16)v;
            }
        }
    }
}

// ---------------------------------------------------------------------------
// Kernel 2: flash-style causal ReLU attention (no softmax -> no rescaling).
// BM=128 queries x BN=64 keys per step; 4 waves, each 32 q-rows.
// ---------------------------------------------------------------------------
__global__ __launch_bounds__(256) void attn(
    const bf16* __restrict__ ws, float* __restrict__ out)
{
    __shared__ bf16 Ks[64 * 72];     // [key][d]
    __shared__ bf16 Vts[64 * 72];    // [d][key]  (transposed)
    __shared__ bf16 Ps[128 * 72];    // [q][key]

    const int tid  = threadIdx.x;
    const int lane = tid & 63;
    const int w    = tid >> 6;
    const int l15  = lane & 15, l4 = lane >> 4;

    // work-balanced mapping: block u and u+256 get complementary q-tiles
    const int u  = blockIdx.x & 255;
    const int hi = blockIdx.x >> 8;
    const int f  = u >> 5;
    const int bh = u & 31;
    const int qt = hi ? (15 - f) : f;

    const bf16* qg = ws + (size_t)bh * (T_SEQ * D_HEAD);
    const bf16* kg = ws + WS_STRIDE + (size_t)bh * (T_SEQ * D_HEAD);
    const bf16* vg = ws + 2 * (size_t)WS_STRIDE + (size_t)bh * (T_SEQ * D_HEAD);
    const int qbase = qt * 128;

    // Q fragments direct global->regs, live across whole K loop
    bf16x8 qF[2][2];
#pragma unroll
    for (int sm = 0; sm < 2; sm++)
#pragma unroll
        for (int kk = 0; kk < 2; kk++)
            qF[sm][kk] = *(const bf16x8*)(qg + (qbase + w * 32 + sm * 16 + l15) * 64
                                          + kk * 32 + l4 * 8);

    f32x4 o[2][4];
#pragma unroll
    for (int sm = 0; sm < 2; sm++)
#pragma unroll
        for (int sd = 0; sd < 4; sd++) o[sm][sd] = (f32x4){0.f, 0.f, 0.f, 0.f};

    // V staging assignment: 2-way-bank (free) transposed dword writes
    const int vp = tid & 31;              // key pair
    const int vc = ((tid >> 5) & 7) * 8;  // d chunk
    const float scale = 0.125f;           // 1/sqrt(64)

    const int jt_max = 2 * qt + 1;
    for (int jt = 0; jt <= jt_max; ++jt) {
        // ---- global loads first (overlap prev MFMAs) ----
        uint4 kd[2];
        int kr[2], kc[2];
#pragma unroll
        for (int e = 0; e < 2; e++) {
            const int idx = tid + e * 256;
            kr[e] = idx >> 3;
            kc[e] = (idx & 7) * 8;
            kd[e] = *(const uint4*)(kg + (jt * 64 + kr[e]) * 64 + kc[e]);
        }
        uint4 va = *(const uint4*)(vg + (jt * 64 + 2 * vp + 0) * 64 + vc);
        uint4 vb = *(const uint4*)(vg + (jt * 64 + 2 * vp + 1) * 64 + vc);

        __syncthreads();   // prev iteration's K/V/P fragment reads complete

#pragma unroll
        for (int e = 0; e < 2; e++)
            *(uint4*)&Ks[kr[e] * 72 + kc[e]] = kd[e];

        const __bf16* pa = reinterpret_cast<const __bf16*>(&va);
        const __bf16* pb = reinterpret_cast<const __bf16*>(&vb);
#pragma unroll
        for (int i = 0; i < 8; i++) {
            union { unsigned int uu; __bf16 h[2]; } pk;
            pk.h[0] = pa[i];
            pk.h[1] = pb[i];
            *reinterpret_cast<unsigned int*>(&Vts[(vc + i) * 72 + 2 * vp]) = pk.uu;
        }
        __syncthreads();   // staging visible

        // ---- S = Q K^T ----
        f32x4 s[2][4];
#pragma unroll
        for (int sm = 0; sm < 2; sm++)
#pragma unroll
            for (int sn = 0; sn < 4; sn++) s[sm][sn] = (f32x4){0.f, 0.f, 0.f, 0.f};
#pragma unroll
        for (int kk = 0; kk < 2; kk++) {
#pragma unroll
            for (int sn = 0; sn < 4; sn++) {
                bf16x8 kF = *(const bf16x8*)&Ks[(sn * 16 + l15) * 72 + kk * 32 + l4 * 8];
#pragma unroll
                for (int sm = 0; sm < 2; sm++)
                    s[sm][sn] = __builtin_amdgcn_mfma_f32_16x16x32_bf16(
                        qF[sm][kk], kF, s[sm][sn], 0, 0, 0);
            }
        }

        // ---- mask + relu + P->LDS (bf16) ----
        const bool need_mask = (jt >= 2 * qt);   // only the two diagonal tiles
#pragma unroll
        for (int sm = 0; sm < 2; sm++) {
#pragma unroll
            for (int sn = 0; sn < 4; sn++) {
                const int n_loc = sn * 16 + l15;
#pragma unroll
                for (int r = 0; r < 4; r++) {
                    const int m_loc = w * 32 + sm * 16 + l4 * 4 + r;
                    float val = fmaxf(s[sm][sn][r] * scale, 0.f);
                    if (need_mask && (qbase + m_loc) < (jt * 64 + n_loc)) val = 0.f;
                    Ps[m_loc * 72 + n_loc] = (__bf16)val;
                }
            }
        }
        __syncthreads();   // P visible

        // ---- O += P V ----
#pragma unroll
        for (int kk = 0; kk < 2; kk++) {
            bf16x8 pF[2];
#pragma unroll
            for (int sm = 0; sm < 2; sm++)
                pF[sm] = *(const bf16x8*)&Ps[(w * 32 + sm * 16 + l15) * 72 + kk * 32 + l4 * 8];
#pragma unroll
            for (int sd = 0; sd < 4; sd++) {
                bf16x8 vF = *(const bf16x8*)&Vts[(sd * 16 + l15) * 72 + kk * 32 + l4 * 8];
#pragma unroll
                for (int sm = 0; sm < 2; sm++)
                    o[sm][sd] = __builtin_amdgcn_mfma_f32_16x16x32_bf16(
                        pF[sm], vF, o[sm][sd], 0, 0, 0);
            }
        }
        // next iteration's first __syncthreads separates these reads from restaging
    }

    // ---- epilogue: O (C-layout) -> out[b][t][h*64+d] fp32 ----
    const int b = bh >> 4, h = bh & 15;
#pragma unroll
    for (int sm = 0; sm < 2; sm++) {
#pragma unroll
        for (int sd = 0; sd < 4; sd++) {
            const int d = sd * 16 + l15;
#pragma unroll
            for (int r = 0; r < 4; r++) {
                const int t = qbase + w * 32 + sm * 16 + l4 * 4 + r;
                out[((size_t)b * T_SEQ + t) * C_EMB + h * 64 + d] = o[sm][sd][r];
            }
        }
    }
}

extern "C" void kernel_launch(void* const* d_in, const int* in_sizes, int n_in,
                              void* d_out, int out_size, void* d_ws, size_t ws_size,
                              hipStream_t stream) {
    const float* x    = (const float*)d_in[0];
    const float* W    = (const float*)d_in[1];
    const float* bias = (const float*)d_in[2];
    float* out        = (float*)d_out;
    bf16*  ws         = (bf16*)d_ws;   // needs 24 MB: q/k/v bf16 [32][2048][64]

    qkv_gemm<<<dim3(768), dim3(256), 0, stream>>>(x, W, bias, ws);
    attn<<<dim3(512), dim3(256), 0, stream>>>(ws, out);
}

// Round 2
// 179.093 us; speedup vs baseline: 1.1919x; 1.1919x over previous
//
#include <hip/hip_runtime.h>

typedef __bf16 bf16;
typedef __bf16 bf16x8 __attribute__((ext_vector_type(8)));
typedef float  f32x4  __attribute__((ext_vector_type(4)));

#define T_SEQ   2048
#define D_HEAD  64
#define NH      16
#define BATCH   2
#define BH      32            // BATCH*NH
#define C_EMB   1024
#define N_TOT   3072
#define WS_STRIDE (BH * T_SEQ * D_HEAD)   // 4,194,304 elems per q/k/v plane
#define XN (4096 * 1024)
#define WN (3072 * 1024)
// ws layout (bf16 elems): [0,3*WS_STRIDE) q/k/v planes; then xb[XN]; then wb[WN]
#define WS_NEEDED ((size_t)(3 * WS_STRIDE + XN + WN) * 2)

__device__ __forceinline__ bf16x8 cvt8(float4 a, float4 b) {
    bf16x8 r;
    r[0] = (__bf16)a.x; r[1] = (__bf16)a.y; r[2] = (__bf16)a.z; r[3] = (__bf16)a.w;
    r[4] = (__bf16)b.x; r[5] = (__bf16)b.y; r[6] = (__bf16)b.z; r[7] = (__bf16)b.w;
    return r;
}

__device__ __forceinline__ void gl_lds16(const bf16* g, bf16* l) {
    __builtin_amdgcn_global_load_lds(
        (const __attribute__((address_space(1))) unsigned int*)g,
        (__attribute__((address_space(3))) unsigned int*)l,
        16, 0, 0);
}

// ---------------------------------------------------------------------------
// Kernel 0: fp32 -> bf16 convert of x and W (memory-bound, ~44 MB traffic)
// ---------------------------------------------------------------------------
__global__ __launch_bounds__(256) void cvt_bf16(
    const float* __restrict__ x, const float* __restrict__ W,
    bf16* __restrict__ xb, bf16* __restrict__ wb)
{
    const int t = blockIdx.x * 256 + threadIdx.x;   // 917504 threads total
    const float* src; bf16* dst; int base;
    if (t < XN / 8) { src = x; dst = xb; base = t * 8; }
    else           { src = W; dst = wb; base = (t - XN / 8) * 8; }
    float4 a = *(const float4*)(src + base);
    float4 b = *(const float4*)(src + base + 4);
    *(bf16x8*)(dst + base) = cvt8(a, b);
}

// ---------------------------------------------------------------------------
// Kernel 1 (fast path): qkv = xb @ wb^T + b, m97-style global_load_lds staging
// 128x128 tile, BK=32, unpadded [128][32] LDS tiles, 2-barrier K-loop.
// ---------------------------------------------------------------------------
__global__ __launch_bounds__(256) void qkv_gemm2(
    const bf16* __restrict__ xb, const bf16* __restrict__ wb,
    const float* __restrict__ bias, bf16* __restrict__ ws)
{
    __shared__ bf16 As[128 * 32];
    __shared__ bf16 Bs[128 * 32];

    const int tid  = threadIdx.x;
    const int lane = tid & 63;
    const int w    = tid >> 6;
    const int wm   = w >> 1, wn = w & 1;
    const int l15  = lane & 15, l4 = lane >> 4;
    const int bm   = blockIdx.x / 24, bn = blockIdx.x % 24;

    // staging: wave w, issue e: row w*32 + e*16 + (lane>>2), col chunk (lane&3)*8
    const int srow = lane >> 2, scol = (lane & 3) * 8;
    const bf16* ag = xb + (size_t)(bm * 128 + w * 32 + srow) * 1024 + scol;
    const bf16* bg = wb + (size_t)(bn * 128 + w * 32 + srow) * 1024 + scol;
    bf16* al = &As[(w * 32) * 32];   // lane*16B offset implicit in global_load_lds
    bf16* bl = &Bs[(w * 32) * 32];

    f32x4 acc[4][4];
#pragma unroll
    for (int i = 0; i < 4; i++)
#pragma unroll
        for (int j = 0; j < 4; j++) acc[i][j] = (f32x4){0.f, 0.f, 0.f, 0.f};

    float bv[4];
#pragma unroll
    for (int j = 0; j < 4; j++) bv[j] = bias[bn * 128 + wn * 64 + j * 16 + l15];

    for (int kk = 0; kk < 32; ++kk) {
        __syncthreads();   // prev iteration's fragment reads complete
        gl_lds16(ag + kk * 32,             al);
        gl_lds16(ag + kk * 32 + 16 * 1024, al + 16 * 32);
        gl_lds16(bg + kk * 32,             bl);
        gl_lds16(bg + kk * 32 + 16 * 1024, bl + 16 * 32);
        __syncthreads();   // drains vmcnt -> staging visible

        bf16x8 aF[4], bF[4];
#pragma unroll
        for (int s = 0; s < 4; s++) {
            aF[s] = *(const bf16x8*)&As[(wm * 64 + s * 16 + l15) * 32 + l4 * 8];
            bF[s] = *(const bf16x8*)&Bs[(wn * 64 + s * 16 + l15) * 32 + l4 * 8];
        }
#pragma unroll
        for (int i = 0; i < 4; i++)
#pragma unroll
            for (int j = 0; j < 4; j++)
                acc[i][j] = __builtin_amdgcn_mfma_f32_16x16x32_bf16(
                    aF[i], bF[j], acc[i][j], 0, 0, 0);
    }

    // epilogue: +bias, scatter bf16 into ws [which][b,h][t][d]
#pragma unroll
    for (int i = 0; i < 4; i++) {
#pragma unroll
        for (int j = 0; j < 4; j++) {
            const int n     = bn * 128 + wn * 64 + j * 16 + l15;
            const int which = n >> 10;
            const int cc    = n & 1023;
            const int h     = cc >> 6, d = cc & 63;
#pragma unroll
            for (int r = 0; r < 4; r++) {
                const int m  = bm * 128 + wm * 64 + i * 16 + l4 * 4 + r;
                const int bi = m >> 11, t = m & 2047;
                const float v = acc[i][j][r] + bv[j];
                ws[which * WS_STRIDE + ((bi * NH + h) * T_SEQ + t) * D_HEAD + d] = (__bf16)v;
            }
        }
    }
}

// ---------------------------------------------------------------------------
// Kernel 1 (fallback, ws too small): round-1 register-convert GEMM
// ---------------------------------------------------------------------------
__global__ __launch_bounds__(256) void qkv_gemm(
    const float* __restrict__ x, const float* __restrict__ W,
    const float* __restrict__ bias, bf16* __restrict__ ws)
{
    __shared__ bf16 As[128 * 40];
    __shared__ bf16 Bs[128 * 40];

    const int tid  = threadIdx.x;
    const int lane = tid & 63;
    const int w    = tid >> 6;
    const int wm   = w >> 1, wn = w & 1;
    const int l15  = lane & 15, l4 = lane >> 4;
    const int bm   = blockIdx.x / 24, bn = blockIdx.x % 24;

    const int srow = tid >> 1;
    const int scol = (tid & 1) * 16;
    const float* xg = x + (size_t)(bm * 128 + srow) * 1024 + scol;
    const float* wg = W + (size_t)(bn * 128 + srow) * 1024 + scol;
    bf16* asw = &As[srow * 40 + scol];
    bf16* bsw = &Bs[srow * 40 + scol];

    f32x4 acc[4][4];
#pragma unroll
    for (int i = 0; i < 4; i++)
#pragma unroll
        for (int j = 0; j < 4; j++) acc[i][j] = (f32x4){0.f, 0.f, 0.f, 0.f};

    float bv[4];
#pragma unroll
    for (int j = 0; j < 4; j++) bv[j] = bias[bn * 128 + wn * 64 + j * 16 + l15];

    for (int kk = 0; kk < 32; ++kk) {
        const float* xp = xg + kk * 32;
        const float* wp = wg + kk * 32;
        float4 a0 = *(const float4*)(xp + 0);
        float4 a1 = *(const float4*)(xp + 4);
        float4 a2 = *(const float4*)(xp + 8);
        float4 a3 = *(const float4*)(xp + 12);
        float4 b0 = *(const float4*)(wp + 0);
        float4 b1 = *(const float4*)(wp + 4);
        float4 b2 = *(const float4*)(wp + 8);
        float4 b3 = *(const float4*)(wp + 12);

        __syncthreads();
        *(bf16x8*)(asw + 0) = cvt8(a0, a1);
        *(bf16x8*)(asw + 8) = cvt8(a2, a3);
        *(bf16x8*)(bsw + 0) = cvt8(b0, b1);
        *(bf16x8*)(bsw + 8) = cvt8(b2, b3);
        __syncthreads();

        bf16x8 aF[4], bF[4];
#pragma unroll
        for (int s = 0; s < 4; s++) {
            aF[s] = *(const bf16x8*)&As[(wm * 64 + s * 16 + l15) * 40 + l4 * 8];
            bF[s] = *(const bf16x8*)&Bs[(wn * 64 + s * 16 + l15) * 40 + l4 * 8];
        }
#pragma unroll
        for (int i = 0; i < 4; i++)
#pragma unroll
            for (int j = 0; j < 4; j++)
                acc[i][j] = __builtin_amdgcn_mfma_f32_16x16x32_bf16(
                    aF[i], bF[j], acc[i][j], 0, 0, 0);
    }

#pragma unroll
    for (int i = 0; i < 4; i++) {
#pragma unroll
        for (int j = 0; j < 4; j++) {
            const int n     = bn * 128 + wn * 64 + j * 16 + l15;
            const int which = n >> 10;
            const int cc    = n & 1023;
            const int h     = cc >> 6, d = cc & 63;
#pragma unroll
            for (int r = 0; r < 4; r++) {
                const int m  = bm * 128 + wm * 64 + i * 16 + l4 * 4 + r;
                const int bi = m >> 11, t = m & 2047;
                const float v = acc[i][j][r] + bv[j];
                ws[which * WS_STRIDE + ((bi * NH + h) * T_SEQ + t) * D_HEAD + d] = (__bf16)v;
            }
        }
    }
}

// ---------------------------------------------------------------------------
// Kernel 2: causal ReLU attention, BM=128, key range split in two halves per
// (bh,qt) -> 1024 blocks; O halves combined via fp32 atomicAdd (out zeroed).
// ---------------------------------------------------------------------------
__global__ __launch_bounds__(256) void attn(
    const bf16* __restrict__ ws, float* __restrict__ out)
{
    __shared__ bf16 Ks[64 * 72];     // [key][d]
    __shared__ bf16 Vts[64 * 72];    // [d][key]  (transposed)
    __shared__ bf16 Ps[128 * 72];    // [q][key]

    const int tid  = threadIdx.x;
    const int lane = tid & 63;
    const int w    = tid >> 6;
    const int l15  = lane & 15, l4 = lane >> 4;

    const int bh   = blockIdx.x & 31;
    const int rest = blockIdx.x >> 5;      // 0..31
    const int qt   = rest >> 1;            // 0..15
    const int half = rest & 1;

    const bf16* qg = ws + (size_t)bh * (T_SEQ * D_HEAD);
    const bf16* kg = ws + WS_STRIDE + (size_t)bh * (T_SEQ * D_HEAD);
    const bf16* vg = ws + 2 * (size_t)WS_STRIDE + (size_t)bh * (T_SEQ * D_HEAD);
    const int qbase = qt * 128;

    // Q fragments direct global->regs, live across whole K loop
    bf16x8 qF[2][2];
#pragma unroll
    for (int sm = 0; sm < 2; sm++)
#pragma unroll
        for (int kk = 0; kk < 2; kk++)
            qF[sm][kk] = *(const bf16x8*)(qg + (qbase + w * 32 + sm * 16 + l15) * 64
                                          + kk * 32 + l4 * 8);

    f32x4 o[2][4];
#pragma unroll
    for (int sm = 0; sm < 2; sm++)
#pragma unroll
        for (int sd = 0; sd < 4; sd++) o[sm][sd] = (f32x4){0.f, 0.f, 0.f, 0.f};

    const int vp = tid & 31;              // key pair
    const int vc = ((tid >> 5) & 7) * 8;  // d chunk
    const float scale = 0.125f;           // 1/sqrt(64)

    // this half handles jt in [half*(qt+1), half*(qt+1)+qt]  (qt+1 tiles)
    const int jt0 = half * (qt + 1);
    const int jt1 = jt0 + qt;
    for (int jt = jt0; jt <= jt1; ++jt) {
        uint4 kd[2];
        int kr[2], kc[2];
#pragma unroll
        for (int e = 0; e < 2; e++) {
            const int idx = tid + e * 256;
            kr[e] = idx >> 3;
            kc[e] = (idx & 7) * 8;
            kd[e] = *(const uint4*)(kg + (jt * 64 + kr[e]) * 64 + kc[e]);
        }
        uint4 va = *(const uint4*)(vg + (jt * 64 + 2 * vp + 0) * 64 + vc);
        uint4 vb = *(const uint4*)(vg + (jt * 64 + 2 * vp + 1) * 64 + vc);

        __syncthreads();   // prev iteration's K/V/P fragment reads complete

#pragma unroll
        for (int e = 0; e < 2; e++)
            *(uint4*)&Ks[kr[e] * 72 + kc[e]] = kd[e];

        const __bf16* pa = reinterpret_cast<const __bf16*>(&va);
        const __bf16* pb = reinterpret_cast<const __bf16*>(&vb);
#pragma unroll
        for (int i = 0; i < 8; i++) {
            union { unsigned int uu; __bf16 h[2]; } pk;
            pk.h[0] = pa[i];
            pk.h[1] = pb[i];
            *reinterpret_cast<unsigned int*>(&Vts[(vc + i) * 72 + 2 * vp]) = pk.uu;
        }
        __syncthreads();   // staging visible

        // ---- S = Q K^T ----
        f32x4 s[2][4];
#pragma unroll
        for (int sm = 0; sm < 2; sm++)
#pragma unroll
            for (int sn = 0; sn < 4; sn++) s[sm][sn] = (f32x4){0.f, 0.f, 0.f, 0.f};
#pragma unroll
        for (int kk = 0; kk < 2; kk++) {
#pragma unroll
            for (int sn = 0; sn < 4; sn++) {
                bf16x8 kF = *(const bf16x8*)&Ks[(sn * 16 + l15) * 72 + kk * 32 + l4 * 8];
#pragma unroll
                for (int sm = 0; sm < 2; sm++)
                    s[sm][sn] = __builtin_amdgcn_mfma_f32_16x16x32_bf16(
                        qF[sm][kk], kF, s[sm][sn], 0, 0, 0);
            }
        }

        // ---- mask + relu + P->LDS (bf16) ----
        const bool need_mask = (jt >= 2 * qt);   // diagonal tiles only
#pragma unroll
        for (int sm = 0; sm < 2; sm++) {
#pragma unroll
            for (int sn = 0; sn < 4; sn++) {
                const int n_loc = sn * 16 + l15;
#pragma unroll
                for (int r = 0; r < 4; r++) {
                    const int m_loc = w * 32 + sm * 16 + l4 * 4 + r;
                    float val = fmaxf(s[sm][sn][r] * scale, 0.f);
                    if (need_mask && (qbase + m_loc) < (jt * 64 + n_loc)) val = 0.f;
                    Ps[m_loc * 72 + n_loc] = (__bf16)val;
                }
            }
        }
        __syncthreads();   // P visible

        // ---- O += P V ----
#pragma unroll
        for (int kk = 0; kk < 2; kk++) {
            bf16x8 pF[2];
#pragma unroll
            for (int sm = 0; sm < 2; sm++)
                pF[sm] = *(const bf16x8*)&Ps[(w * 32 + sm * 16 + l15) * 72 + kk * 32 + l4 * 8];
#pragma unroll
            for (int sd = 0; sd < 4; sd++) {
                bf16x8 vF = *(const bf16x8*)&Vts[(sd * 16 + l15) * 72 + kk * 32 + l4 * 8];
#pragma unroll
                for (int sm = 0; sm < 2; sm++)
                    o[sm][sd] = __builtin_amdgcn_mfma_f32_16x16x32_bf16(
                        pF[sm], vF, o[sm][sd], 0, 0, 0);
            }
        }
    }

    // ---- epilogue: atomic-accumulate O into out[b][t][h*64+d] ----
    const int b = bh >> 4, h = bh & 15;
#pragma unroll
    for (int sm = 0; sm < 2; sm++) {
#pragma unroll
        for (int sd = 0; sd < 4; sd++) {
            const int d = sd * 16 + l15;
#pragma unroll
            for (int r = 0; r < 4; r++) {
                const int t = qbase + w * 32 + sm * 16 + l4 * 4 + r;
                unsafeAtomicAdd(&out[((size_t)b * T_SEQ + t) * C_EMB + h * 64 + d],
                                o[sm][sd][r]);
            }
        }
    }
}

extern "C" void kernel_launch(void* const* d_in, const int* in_sizes, int n_in,
                              void* d_out, int out_size, void* d_ws, size_t ws_size,
                              hipStream_t stream) {
    const float* x    = (const float*)d_in[0];
    const float* W    = (const float*)d_in[1];
    const float* bias = (const float*)d_in[2];
    float* out        = (float*)d_out;
    bf16*  ws         = (bf16*)d_ws;

    if (ws_size >= WS_NEEDED) {
        bf16* xb = ws + 3 * (size_t)WS_STRIDE;
        bf16* wb = xb + XN;
        cvt_bf16<<<dim3(3584), dim3(256), 0, stream>>>(x, W, xb, wb);
        qkv_gemm2<<<dim3(768), dim3(256), 0, stream>>>(xb, wb, bias, ws);
    } else {
        qkv_gemm<<<dim3(768), dim3(256), 0, stream>>>(x, W, bias, ws);
    }
    hipMemsetAsync(out, 0, (size_t)out_size * sizeof(float), stream);
    attn<<<dim3(1024), dim3(256), 0, stream>>>(ws, out);
}